// Round 11
// baseline (359.394 us; speedup 1.0000x reference)
//
#include <hip/hip_runtime.h>
#include <stdint.h>

#define R_ 64
#define C_ 512
#define E_ 768
#define H_ 12
#define D_ 64
#define M_TOT (R_*C_)   // 32768

using short4v = __attribute__((ext_vector_type(4))) short;
using short8  = __attribute__((ext_vector_type(8))) short;
using f32x4   = __attribute__((ext_vector_type(4))) float;
using floatv4 = __attribute__((ext_vector_type(4))) float;

#define MFMA16(a,b,c) __builtin_amdgcn_mfma_f32_16x16x32_bf16(a,b,c,0,0,0)

__device__ __forceinline__ short f2bf(float f){
  union { float f; unsigned u; } c; c.f = f;
  unsigned u = c.u;
  u += 0x7fffu + ((u >> 16) & 1u);   // RNE
  return (short)(u >> 16);
}

// async global->LDS, 16B per lane. LDS dest is wave-uniform base; HW adds lane*16.
__device__ __forceinline__ void gload16(const void* g, void* lds){
  __builtin_amdgcn_global_load_lds(
      (const __attribute__((address_space(1))) void*)(uintptr_t)g,
      (__attribute__((address_space(3))) void*)(uint32_t)(uintptr_t)lds,
      16, 0, 0);
}

struct Lin {
  const short* p; int ld;
  __device__ __forceinline__ const short* at(int r, int c) const {
    return p + (long)r * ld + c;
  }
};
// oproj A operand: ctx stored as ctx_t[h][i][r*64+d]; m = r*512+i, k = h*64+d
struct CtxMap {
  const short* p;
  __device__ __forceinline__ const short* at(int m, int k) const {
    return p + ((long)((k >> 6) * 512 + (m & 511))) * 4096 + ((m >> 9) << 6) + (k & 63);
  }
};

// ---------------------------------------------------------------------------
// 4-phase-per-K-tile deep-pipelined GEMM core (used by logits/ctx/oproj).
// BM=256, BN=128, BK=64. 512 threads = 8 waves (4M x 2N). (r3 core, proven.)
// ---------------------------------------------------------------------------
template<class AT, class BT>
__device__ __forceinline__ void gemm_core(
    const AT& A, const BT& B, int m0, int n0, int K,
    short* smem, f32x4 (&acc)[4][4])
{
  const int t = threadIdx.x, l = t & 63, w = t >> 6;
  const int wm = w >> 1, wn = w & 1;
  const int g_row8 = t >> 3;
  const int cg = t & 7;

  auto stageA = [&](int kt, int buf, int u){
    const int row = u*64 + g_row8;
    const int sc  = ((cg ^ (row & 7)) << 3);
    gload16(A.at(m0 + row, kt*64 + sc), smem + buf*16384 + u*4096 + w*512);
  };
  auto stageB = [&](int kt, int buf, int u){
    const int row = u*64 + g_row8;
    const int sc  = ((cg ^ (row & 7)) << 3);
    gload16(B.at(n0 + row, kt*64 + sc), smem + 49152 + buf*8192 + u*4096 + w*512);
  };

  const int NT = K >> 6;
  #pragma unroll
  for (int u = 0; u < 4; ++u) stageA(0, 0, u);
  #pragma unroll
  for (int u = 0; u < 2; ++u) stageB(0, 0, u);
  #pragma unroll
  for (int u = 0; u < 4; ++u) stageA(1, 1, u);
  #pragma unroll
  for (int u = 0; u < 2; ++u) stageB(1, 1, u);
  asm volatile("s_waitcnt vmcnt(6)" ::: "memory");
  __builtin_amdgcn_s_barrier();
  asm volatile("" ::: "memory");

  int cur = 0;
  for (int kt = 0; kt < NT; ++kt){
    const int tgt = (cur == 0) ? 2 : cur - 1;
    const bool pf = (kt + 2 < NT);
    const char* cA = (const char*)(smem + cur * 16384);
    const char* cB = (const char*)(smem + 49152 + cur * 8192);

    auto rdA = [&](int m, int ks)->short8{
      const int r = wm*64 + m*16 + (l & 15);
      const int g = (ks*4 + (l >> 4)) ^ (r & 7);
      return *(const short8*)(cA + r*128 + g*16);
    };
    auto rdB = [&](int n, int ks)->short8{
      const int r = wn*64 + n*16 + (l & 15);
      const int g = (ks*4 + (l >> 4)) ^ (r & 7);
      return *(const short8*)(cB + r*128 + g*16);
    };

    short8 af0a, af0b, af1a, af1b, af2a, af2b, af3a, af3b;
    short8 bf0a, bf0b, bf1a, bf1b, bf2a, bf2b, bf3a, bf3b;

    // phase 0
    af0a = rdA(0,0); af0b = rdA(0,1); af1a = rdA(1,0); af1b = rdA(1,1);
    bf0a = rdB(0,0); bf0b = rdB(0,1); bf1a = rdB(1,0); bf1b = rdB(1,1);
    if (pf){ stageA(kt+2, tgt, 0); stageA(kt+2, tgt, 1); }
    __builtin_amdgcn_s_barrier();
    __builtin_amdgcn_sched_barrier(0);
    __builtin_amdgcn_s_setprio(1);
    acc[0][0] = MFMA16(af0a, bf0a, acc[0][0]); acc[0][0] = MFMA16(af0b, bf0b, acc[0][0]);
    acc[0][1] = MFMA16(af0a, bf1a, acc[0][1]); acc[0][1] = MFMA16(af0b, bf1b, acc[0][1]);
    acc[1][0] = MFMA16(af1a, bf0a, acc[1][0]); acc[1][0] = MFMA16(af1b, bf0b, acc[1][0]);
    acc[1][1] = MFMA16(af1a, bf1a, acc[1][1]); acc[1][1] = MFMA16(af1b, bf1b, acc[1][1]);
    __builtin_amdgcn_s_setprio(0);
    __builtin_amdgcn_s_barrier();
    asm volatile("" ::: "memory");

    // phase 1
    bf2a = rdB(2,0); bf2b = rdB(2,1); bf3a = rdB(3,0); bf3b = rdB(3,1);
    if (pf){ stageA(kt+2, tgt, 2); stageA(kt+2, tgt, 3); }
    __builtin_amdgcn_s_barrier();
    __builtin_amdgcn_sched_barrier(0);
    __builtin_amdgcn_s_setprio(1);
    acc[0][2] = MFMA16(af0a, bf2a, acc[0][2]); acc[0][2] = MFMA16(af0b, bf2b, acc[0][2]);
    acc[0][3] = MFMA16(af0a, bf3a, acc[0][3]); acc[0][3] = MFMA16(af0b, bf3b, acc[0][3]);
    acc[1][2] = MFMA16(af1a, bf2a, acc[1][2]); acc[1][2] = MFMA16(af1b, bf2b, acc[1][2]);
    acc[1][3] = MFMA16(af1a, bf3a, acc[1][3]); acc[1][3] = MFMA16(af1b, bf3b, acc[1][3]);
    __builtin_amdgcn_s_setprio(0);
    __builtin_amdgcn_s_barrier();
    asm volatile("" ::: "memory");

    // phase 2
    af2a = rdA(2,0); af2b = rdA(2,1); af3a = rdA(3,0); af3b = rdA(3,1);
    if (pf){ stageB(kt+2, tgt, 0); stageB(kt+2, tgt, 1); }
    __builtin_amdgcn_s_barrier();
    __builtin_amdgcn_sched_barrier(0);
    __builtin_amdgcn_s_setprio(1);
    acc[2][2] = MFMA16(af2a, bf2a, acc[2][2]); acc[2][2] = MFMA16(af2b, bf2b, acc[2][2]);
    acc[2][3] = MFMA16(af2a, bf3a, acc[2][3]); acc[2][3] = MFMA16(af2b, bf3b, acc[2][3]);
    acc[3][2] = MFMA16(af3a, bf2a, acc[3][2]); acc[3][2] = MFMA16(af3b, bf2b, acc[3][2]);
    acc[3][3] = MFMA16(af3a, bf3a, acc[3][3]); acc[3][3] = MFMA16(af3b, bf3b, acc[3][3]);
    __builtin_amdgcn_s_setprio(0);
    __builtin_amdgcn_s_barrier();
    asm volatile("" ::: "memory");

    // phase 3
    __builtin_amdgcn_s_setprio(1);
    acc[2][0] = MFMA16(af2a, bf0a, acc[2][0]); acc[2][0] = MFMA16(af2b, bf0b, acc[2][0]);
    acc[2][1] = MFMA16(af2a, bf1a, acc[2][1]); acc[2][1] = MFMA16(af2b, bf1b, acc[2][1]);
    acc[3][0] = MFMA16(af3a, bf0a, acc[3][0]); acc[3][0] = MFMA16(af3b, bf0b, acc[3][0]);
    acc[3][1] = MFMA16(af3a, bf1a, acc[3][1]); acc[3][1] = MFMA16(af3b, bf1b, acc[3][1]);
    __builtin_amdgcn_s_setprio(0);
    if (pf) asm volatile("s_waitcnt vmcnt(6)" ::: "memory");
    else    asm volatile("s_waitcnt vmcnt(0)" ::: "memory");
    __builtin_amdgcn_s_barrier();
    asm volatile("" ::: "memory");
    cur = (cur == 2) ? 0 : cur + 1;
  }
}

#define ACC_INIT(acc) \
  _Pragma("unroll") for (int m_=0;m_<4;m_++) _Pragma("unroll") for (int n_=0;n_<4;n_++) \
    acc[m_][n_] = (f32x4){0.f,0.f,0.f,0.f};

// ---------------------------------------------------------------------------
// weight f32->bf16; Wq pre-scaled by 1/64.
// ---------------------------------------------------------------------------
__global__ __launch_bounds__(256) void cvt_w_k(
    const float* __restrict__ Wq, const float* __restrict__ Wk,
    const float* __restrict__ Wv, const float* __restrict__ Wo,
    short* __restrict__ out)
{
  const int i = blockIdx.x * blockDim.x + threadIdx.x;
  const int wsel = i / 73728, j = i - wsel * 73728;
  const float* src = (wsel == 0) ? Wq : (wsel == 1) ? Wk : (wsel == 2) ? Wv : Wo;
  const float scale = (wsel == 0) ? 0.015625f : 1.0f;
  floatv4 a = *(const floatv4*)(src + (long)j*8);
  floatv4 b = *(const floatv4*)(src + (long)j*8 + 4);
  short8 s;
  #pragma unroll
  for (int q = 0; q < 4; ++q){ s[q] = f2bf(a[q]*scale); s[4+q] = f2bf(b[q]*scale); }
  *(short8*)(out + (long)i*8) = s;
}

// ---------------------------------------------------------------------------
// Fused q/k/v projection (r6 best structure), with A (x) reg-staged from f32
// directly: f32 loads issued phase 0 (tile t+2), cvt+ds_write in phase 2 —
// removes the standalone x-conversion kernel.
// BM=256, BN=128 (x3 proj), BK=32. LDS: A 3 bufs x 16KB @0,
// B 3 bufs x 24KB (3 x 8KB) @24576 shorts. 120 KB total.
// Row-pair 128B-line swizzle: slot = ((row&1)*4 + g) ^ (line&7).
// Waits: implicit vmcnt at p2's fA read drains t+1's B stages; explicit
// tile-end vmcnt(3) keeps t's 3 B-gload_lds in flight; vmcnt(0) in tail.
// ds_write visibility: writer's later lgkm waits drain it >=2 barriers
// before cross-wave consumption at tile t+2.
// ---------------------------------------------------------------------------
__global__ __launch_bounds__(512, 2) void proj_fused_k(
    const float* __restrict__ xf, const short* __restrict__ wb,
    const float* __restrict__ bq, const float* __restrict__ bk, const float* __restrict__ bv,
    short* __restrict__ qt, short* __restrict__ kt, short* __restrict__ vtt)
{
  __shared__ short smem[61440];
  const int bid = blockIdx.x;
  const int xcd = bid & 7, idx = bid >> 3;        // idx 0..95
  const int mlocal = idx / 6, n = idx % 6;
  const int m0 = (xcd * 16 + mlocal) * 256;
  const int n0 = n * 128;

  const int t = threadIdx.x, l = t & 63, w = t >> 6;
  const int wm = w >> 1, wn = w & 1;
  const int lsub = l >> 3;           // line within instr (0..7)
  const int sslot = l & 7;           // slot within line

  floatv4 fA[2][2];                  // [u][half] in-flight A f32 data

  auto aload = [&](int kt_, int u){
    const int L = (w*2 + u)*8 + lsub;            // line 0..127
    const int v = sslot ^ (L & 7);
    const int row = L*2 + (v >> 2);
    const int g = v & 3;
    const float* src = xf + (long)(m0 + row)*E_ + kt_*32 + g*8;
    fA[u][0] = *(const floatv4*)(src);
    fA[u][1] = *(const floatv4*)(src + 4);
  };
  auto awrite = [&](int buf, int u){
    short8 s;
    #pragma unroll
    for (int j = 0; j < 4; ++j){ s[j] = f2bf(fA[u][0][j]); s[4+j] = f2bf(fA[u][1][j]); }
    *(short8*)(smem + buf*8192 + (w*2 + u)*512 + l*8) = s;
  };
  auto stageB = [&](int kt_, int buf, int p){
    const int L = w*8 + lsub;                    // line 0..63
    const int v = sslot ^ (L & 7);
    const int row = L*2 + (v >> 2);
    const int g = v & 3;
    gload16(wb + (long)p*E_*E_ + (long)(n0 + row)*E_ + kt_*32 + g*8,
            smem + 24576 + buf*12288 + p*4096 + w*512);
  };

  f32x4 acc[3][4][4];
  #pragma unroll
  for (int p = 0; p < 3; ++p) ACC_INIT(acc[p]);

  const int NT = E_ / 32;   // 24
  // prologue: tiles 0,1 (A inline cvt; B async)
  aload(0,0); aload(0,1); awrite(0,0); awrite(0,1);
  aload(1,0); aload(1,1); awrite(1,0); awrite(1,1);
  stageB(0,0,0); stageB(0,0,1); stageB(0,0,2);
  stageB(1,1,0); stageB(1,1,1); stageB(1,1,2);
  asm volatile("s_waitcnt vmcnt(0) lgkmcnt(0)" ::: "memory");
  __builtin_amdgcn_s_barrier();
  asm volatile("" ::: "memory");

  int cur = 0;
  for (int kt_ = 0; kt_ < NT; ++kt_){
    const int tgt = (cur == 0) ? 2 : cur - 1;
    const bool pf = (kt_ + 2 < NT);
    const char* cA = (const char*)(smem + cur * 8192);
    const char* cB = (const char*)(smem + 24576 + cur * 12288);

    auto rdA = [&](int m)->short8{
      const int r = wm*64 + m*16 + (l & 15);
      const int g = l >> 4;
      const int L = r >> 1;
      const int s = ((r & 1)*4 + g) ^ (L & 7);
      return *(const short8*)(cA + L*128 + s*16);
    };
    auto rdB = [&](int p, int nn)->short8{
      const int r = wn*64 + nn*16 + (l & 15);
      const int g = l >> 4;
      const int L = r >> 1;
      const int s = ((r & 1)*4 + g) ^ (L & 7);
      return *(const short8*)(cB + p*8192 + L*128 + s*16);
    };

    short8 af0, af1, af2, af3, b0, b1, b2, b3;

    // ---- phase 0: proj q. read A+Bq frags; ISSUE A f32 loads for t+2
    af0 = rdA(0); af1 = rdA(1); af2 = rdA(2); af3 = rdA(3);
    b0 = rdB(0,0); b1 = rdB(0,1); b2 = rdB(0,2); b3 = rdB(0,3);
    if (pf){ aload(kt_+2, 0); aload(kt_+2, 1); }
    __builtin_amdgcn_s_barrier();
    __builtin_amdgcn_sched_barrier(0);
    __builtin_amdgcn_s_setprio(1);
    acc[0][0][0] = MFMA16(af0, b0, acc[0][0][0]); acc[0][0][1] = MFMA16(af0, b1, acc[0][0][1]);
    acc[0][0][2] = MFMA16(af0, b2, acc[0][0][2]); acc[0][0][3] = MFMA16(af0, b3, acc[0][0][3]);
    acc[0][1][0] = MFMA16(af1, b0, acc[0][1][0]); acc[0][1][1] = MFMA16(af1, b1, acc[0][1][1]);
    acc[0][1][2] = MFMA16(af1, b2, acc[0][1][2]); acc[0][1][3] = MFMA16(af1, b3, acc[0][1][3]);
    acc[0][2][0] = MFMA16(af2, b0, acc[0][2][0]); acc[0][2][1] = MFMA16(af2, b1, acc[0][2][1]);
    acc[0][2][2] = MFMA16(af2, b2, acc[0][2][2]); acc[0][2][3] = MFMA16(af2, b3, acc[0][2][3]);
    acc[0][3][0] = MFMA16(af3, b0, acc[0][3][0]); acc[0][3][1] = MFMA16(af3, b1, acc[0][3][1]);
    acc[0][3][2] = MFMA16(af3, b2, acc[0][3][2]); acc[0][3][3] = MFMA16(af3, b3, acc[0][3][3]);
    __builtin_amdgcn_s_setprio(0);
    __builtin_amdgcn_s_barrier();
    asm volatile("" ::: "memory");

    // ---- phase 1: proj k. read Bk frags; stage B p0,p1 (t+2)
    b0 = rdB(1,0); b1 = rdB(1,1); b2 = rdB(1,2); b3 = rdB(1,3);
    if (pf){ stageB(kt_+2, tgt, 0); stageB(kt_+2, tgt, 1); }
    __builtin_amdgcn_s_barrier();
    __builtin_amdgcn_sched_barrier(0);
    __builtin_amdgcn_s_setprio(1);
    acc[1][0][0] = MFMA16(af0, b0, acc[1][0][0]); acc[1][0][1] = MFMA16(af0, b1, acc[1][0][1]);
    acc[1][0][2] = MFMA16(af0, b2, acc[1][0][2]); acc[1][0][3] = MFMA16(af0, b3, acc[1][0][3]);
    acc[1][1][0] = MFMA16(af1, b0, acc[1][1][0]); acc[1][1][1] = MFMA16(af1, b1, acc[1][1][1]);
    acc[1][1][2] = MFMA16(af1, b2, acc[1][1][2]); acc[1][1][3] = MFMA16(af1, b3, acc[1][1][3]);
    acc[1][2][0] = MFMA16(af2, b0, acc[1][2][0]); acc[1][2][1] = MFMA16(af2, b1, acc[1][2][1]);
    acc[1][2][2] = MFMA16(af2, b2, acc[1][2][2]); acc[1][2][3] = MFMA16(af2, b3, acc[1][2][3]);
    acc[1][3][0] = MFMA16(af3, b0, acc[1][3][0]); acc[1][3][1] = MFMA16(af3, b1, acc[1][3][1]);
    acc[1][3][2] = MFMA16(af3, b2, acc[1][3][2]); acc[1][3][3] = MFMA16(af3, b3, acc[1][3][3]);
    __builtin_amdgcn_s_setprio(0);
    __builtin_amdgcn_s_barrier();
    asm volatile("" ::: "memory");

    // ---- phase 2: proj v. read Bv frags; WRITE A (cvt) + stage B p2 (t+2)
    b0 = rdB(2,0); b1 = rdB(2,1); b2 = rdB(2,2); b3 = rdB(2,3);
    if (pf){ awrite(tgt, 0); awrite(tgt, 1); stageB(kt_+2, tgt, 2); }
    __builtin_amdgcn_s_barrier();
    __builtin_amdgcn_sched_barrier(0);
    __builtin_amdgcn_s_setprio(1);
    acc[2][0][0] = MFMA16(af0, b0, acc[2][0][0]); acc[2][0][1] = MFMA16(af0, b1, acc[2][0][1]);
    acc[2][0][2] = MFMA16(af0, b2, acc[2][0][2]); acc[2][0][3] = MFMA16(af0, b3, acc[2][0][3]);
    acc[2][1][0] = MFMA16(af1, b0, acc[2][1][0]); acc[2][1][1] = MFMA16(af1, b1, acc[2][1][1]);
    acc[2][1][2] = MFMA16(af1, b2, acc[2][1][2]); acc[2][1][3] = MFMA16(af1, b3, acc[2][1][3]);
    acc[2][2][0] = MFMA16(af2, b0, acc[2][2][0]); acc[2][2][1] = MFMA16(af2, b1, acc[2][2][1]);
    acc[2][2][2] = MFMA16(af2, b2, acc[2][2][2]); acc[2][2][3] = MFMA16(af2, b3, acc[2][2][3]);
    acc[2][3][0] = MFMA16(af3, b0, acc[2][3][0]); acc[2][3][1] = MFMA16(af3, b1, acc[2][3][1]);
    acc[2][3][2] = MFMA16(af3, b2, acc[2][3][2]); acc[2][3][3] = MFMA16(af3, b3, acc[2][3][3]);
    __builtin_amdgcn_s_setprio(0);
    if (pf) asm volatile("s_waitcnt vmcnt(3)" ::: "memory");
    else    asm volatile("s_waitcnt vmcnt(0)" ::: "memory");
    __builtin_amdgcn_s_barrier();
    asm volatile("" ::: "memory");
    cur = (cur == 2) ? 0 : cur + 1;
  }

  // ---------------- epilogue (r6 best: q/k scatter, v LDS bounce) ----------
  const int wr = wm * 64, wc = wn * 64;

  #pragma unroll
  for (int p = 0; p < 2; ++p){
    const float* bias = (p == 0) ? bq : bk;
    short* outp = (p == 0) ? qt : kt;
    const float sc = (p == 0) ? 0.015625f : 1.0f;
    #pragma unroll
    for (int nn = 0; nn < 4; ++nn){
      const int gc = n0 + wc + nn*16 + (l & 15);
      const float bb = bias[gc] * sc;
      const int h = gc >> 6, d = gc & 63;
      #pragma unroll
      for (int m = 0; m < 4; ++m){
        #pragma unroll
        for (int rg = 0; rg < 4; ++rg){
          const int gm = m0 + wr + m*16 + (l >> 4)*4 + rg;
          const int i = gm & 511, r = gm >> 9;
          outp[((long)(h*512 + i))*4096 + r*64 + d] = f2bf(acc[p][m][nn][rg] + bb);
        }
      }
    }
  }

  // v: LDS bounce -> coalesced vtt[h][r*64+d][j] rows.
  {
    short* ldsv = smem;
    #pragma unroll
    for (int nn = 0; nn < 4; ++nn){
      const int dl = wc + nn*16 + (l & 15);
      const float bb = bv[n0 + dl];
      #pragma unroll
      for (int m = 0; m < 4; ++m){
        const int j = wr + m*16 + (l >> 4)*4;
        short4v s;
        #pragma unroll
        for (int rg = 0; rg < 4; ++rg) s[rg] = f2bf(acc[2][m][nn][rg] + bb);
        const int byteoff = dl*512 + (((j >> 3) ^ (dl & 31)) << 4) + (j & 7)*2;
        *(short4v*)((char*)ldsv + byteoff) = s;
      }
    }
    __builtin_amdgcn_s_barrier();
    const int dl = t & 127, chunk = t >> 7;     // 4 chunks of 64 shorts
    const int gd = n0 + dl;
    const int h = gd >> 6, dd = gd & 63;
    const int r = m0 >> 9, i0 = m0 & 511;
    short* dst = vtt + ((long)h*4096 + r*64 + dd)*512 + i0 + chunk*64;
    #pragma unroll
    for (int q = 0; q < 8; ++q){
      const int c16 = chunk*8 + q;
      short8 vv = *(const short8*)((const char*)ldsv + dl*512 + ((c16 ^ (dl & 31)) << 4));
      *(short8*)(dst + q*8) = vv;
    }
  }
}

// ---------------------------------------------------------------------------
// Logits split-K x2. 1-D grid 192; z-grouped on XCDs. Partials -> out scratch.
// ---------------------------------------------------------------------------
__global__ __launch_bounds__(512, 2) void logits_k(
    const short* __restrict__ qt, const short* __restrict__ kt,
    float* __restrict__ P0, float* __restrict__ P1)
{
  __shared__ short smem[73728];
  const int bid = blockIdx.x;
  const int xcd = bid & 7, idx = bid >> 3;        // idx 0..23
  const int z = xcd * 3 + idx / 8;                // 0..23
  const int local = idx & 7;
  const int h = z >> 1, s = z & 1;
  const int m0 = (local >> 2) * 256, n0 = (local & 3) * 128;

  f32x4 acc[4][4]; ACC_INIT(acc);
  Lin A{qt + (long)h * C_ * 4096 + s*2048, 4096};
  Lin B{kt + (long)h * C_ * 4096 + s*2048, 4096};
  gemm_core(A, B, m0, n0, 2048, smem, acc);

  float* Sh = ((s == 0) ? P0 : P1) + (long)h * C_ * C_;
  const int t = threadIdx.x, l = t & 63, w = t >> 6;
  const int wr = (w >> 1) * 64, wc = (w & 1) * 64;
  #pragma unroll
  for (int m = 0; m < 4; ++m){
    #pragma unroll
    for (int n = 0; n < 4; ++n){
      #pragma unroll
      for (int rg = 0; rg < 4; ++rg){
        const int gi = m0 + wr + m*16 + (l >> 4)*4 + rg;
        const int gj = n0 + wc + n*16 + (l & 15);
        Sh[(long)gi * C_ + gj] = acc[m][n][rg];
      }
    }
  }
}

// ---------------------------------------------------------------------------
__global__ __launch_bounds__(256) void softmax4_k(
    const float* __restrict__ S0, const float* __restrict__ S1,
    float* __restrict__ probs, short* __restrict__ Pbf)
{
  const int row = blockIdx.x;       // h*512 + i
  const int i = row & 511;
  const long base = (long)row * C_;
  const int t = threadIdx.x, lane = t & 63, wid = t >> 6;
  __shared__ float red[4];

  float v0 = S0[base + t]       + S1[base + t];
  float v1 = S0[base + t + 256] + S1[base + t + 256];
  if (t == i)       v0 = -1e9f;
  if (t + 256 == i) v1 = -1e9f;

  float mx = fmaxf(v0, v1);
  #pragma unroll
  for (int m = 1; m < 64; m <<= 1) mx = fmaxf(mx, __shfl_xor(mx, m, 64));
  if (lane == 0) red[wid] = mx;
  __syncthreads();
  mx = fmaxf(fmaxf(red[0], red[1]), fmaxf(red[2], red[3]));
  __syncthreads();

  float e0 = __expf(v0 - mx), e1 = __expf(v1 - mx);
  float ssum = e0 + e1;
  #pragma unroll
  for (int m = 1; m < 64; m <<= 1) ssum += __shfl_xor(ssum, m, 64);
  if (lane == 0) red[wid] = ssum;
  __syncthreads();
  const float inv = 1.0f / (red[0] + red[1] + red[2] + red[3]);

  const float p0 = e0 * inv, p1 = e1 * inv;
  probs[base + t] = p0; probs[base + t + 256] = p1;
  Pbf[base + t] = f2bf(p0);
  Pbf[base + t + 256] = f2bf(p1);
}

// ---------------------------------------------------------------------------
__global__ __launch_bounds__(512, 2) void ctx_k(
    const short* __restrict__ pb, const short* __restrict__ vtt, short* __restrict__ ctx_t)
{
  __shared__ short smem[73728];
  const int bid = blockIdx.x;
  const int seq = (bid & 7) * 96 + (bid >> 3);    // 0..767
  const int h = seq >> 6, local = seq & 63;
  const int m0 = (local >> 5) * 256, n0 = (local & 31) * 128;

  f32x4 acc[4][4]; ACC_INIT(acc);
  Lin A{pb + (long)h * C_ * C_, C_};
  Lin B{vtt + (long)h * 4096 * C_, C_};
  gemm_core(A, B, m0, n0, C_, smem, acc);

  const int t = threadIdx.x, l = t & 63, w = t >> 6;
  const int wr = (w >> 1) * 64, wc = (w & 1) * 64;
  short* outh = ctx_t + (long)h * C_ * 4096;
  #pragma unroll
  for (int m = 0; m < 4; ++m){
    #pragma unroll
    for (int n = 0; n < 4; ++n){
      #pragma unroll
      for (int rg = 0; rg < 4; ++rg){
        const int gi = m0 + wr + m*16 + (l >> 4)*4 + rg;
        const int gn = n0 + wc + n*16 + (l & 15);
        outh[(long)gi * 4096 + gn] = f2bf(acc[m][n][rg]);
      }
    }
  }
}

// ---------------------------------------------------------------------------
__global__ __launch_bounds__(512, 2) void oproj_k(
    const short* __restrict__ ctx_t, const short* __restrict__ wo,
    const float* __restrict__ bo, float* __restrict__ out)
{
  __shared__ short smem[73728];
  const int bid = blockIdx.x;
  const int xcd = bid & 7, idx = bid >> 3;        // 0..95
  const int m0 = (xcd * 16 + idx / 6) * 256;
  const int n0 = (idx % 6) * 128;

  f32x4 acc[4][4]; ACC_INIT(acc);
  CtxMap A{ctx_t};
  Lin B{wo, E_};
  gemm_core(A, B, m0, n0, E_, smem, acc);

  const int t = threadIdx.x, l = t & 63, w = t >> 6;
  const int wr = (w >> 1) * 64, wc = (w & 1) * 64;
  #pragma unroll
  for (int n = 0; n < 4; ++n){
    const int gc = n0 + wc + n*16 + (l & 15);
    const float bb = bo[gc];
    #pragma unroll
    for (int m = 0; m < 4; ++m){
      #pragma unroll
      for (int rg = 0; rg < 4; ++rg){
        const int gm = m0 + wr + m*16 + (l >> 4)*4 + rg;
        out[(long)gm * E_ + gc] = acc[m][n][rg] + bb;
      }
    }
  }
}

// ---------------------------------------------------------------------------
extern "C" void kernel_launch(void* const* d_in, const int* in_sizes, int n_in,
                              void* d_out, int out_size, void* d_ws, size_t ws_size,
                              hipStream_t stream)
{
  const float* x  = (const float*)d_in[0];
  const float* Wq = (const float*)d_in[2];
  const float* bq = (const float*)d_in[3];
  const float* Wk = (const float*)d_in[4];
  const float* bk = (const float*)d_in[5];
  const float* Wv = (const float*)d_in[6];
  const float* bv = (const float*)d_in[7];
  const float* Wo = (const float*)d_in[8];
  const float* bo = (const float*)d_in[9];
  const float* l  = (const float*)d_in[10];

  float* out   = (float*)d_out;                          // [32768][768]
  float* probs = out + (size_t)M_TOT * E_;               // [12][512][512] f32
  float* lout  = probs + (size_t)H_ * C_ * C_;           // [12]

  // out-region scratch (dead until oproj): two logits partials + vtt
  float* P0  = out;                                      // 12.6 MB
  float* P1  = out + 3145728;                            // 12.6 MB
  short* vtt = (short*)(out + 6291456);                  // 50.3 MB bf16

  short* ws_s = (short*)d_ws;
  const size_t SLOT = (size_t)M_TOT * E_;                // 25,165,824 elems
  short* s1 = ws_s + SLOT;         // qt -> ctx_t
  short* s2 = ws_s + 2*SLOT;       // kt -> pb
  short* wb = ws_s + 3*SLOT;       // 4 x 589824 bf16 weights

  hipMemcpyAsync(lout, l, H_ * sizeof(float), hipMemcpyDeviceToDevice, stream);

  cvt_w_k<<<1152, 256, 0, stream>>>(Wq, Wk, Wv, Wo, wb);

  proj_fused_k<<<768, 512, 0, stream>>>(x, wb, bq, bk, bv, s1, s2, vtt);
  logits_k<<<192, 512, 0, stream>>>(s1, s2, P0, P1);
  softmax4_k<<<H_ * C_, 256, 0, stream>>>(P0, P1, probs, s2);
  ctx_k<<<768, 512, 0, stream>>>(s2, vtt, s1);
  oproj_k<<<768, 512, 0, stream>>>(s1, wb + 3*589824, bo, out);
}

// Round 12
// 306.321 us; speedup vs baseline: 1.1733x; 1.1733x over previous
//
#include <hip/hip_runtime.h>
#include <stdint.h>

#define R_ 64
#define C_ 512
#define E_ 768
#define H_ 12
#define D_ 64
#define M_TOT (R_*C_)   // 32768

using short4v = __attribute__((ext_vector_type(4))) short;
using short8  = __attribute__((ext_vector_type(8))) short;
using f32x4   = __attribute__((ext_vector_type(4))) float;
using f32x16  = __attribute__((ext_vector_type(16))) float;
using floatv4 = __attribute__((ext_vector_type(4))) float;

#define MFMA16(a,b,c) __builtin_amdgcn_mfma_f32_16x16x32_bf16(a,b,c,0,0,0)
#define MFMA32(a,b,c) __builtin_amdgcn_mfma_f32_32x32x16_bf16(a,b,c,0,0,0)

__device__ __forceinline__ short f2bf(float f){
  union { float f; unsigned u; } c; c.f = f;
  unsigned u = c.u;
  u += 0x7fffu + ((u >> 16) & 1u);   // RNE
  return (short)(u >> 16);
}

// async global->LDS, 16B per lane. LDS dest is wave-uniform base; HW adds lane*16.
__device__ __forceinline__ void gload16(const void* g, void* lds){
  __builtin_amdgcn_global_load_lds(
      (const __attribute__((address_space(1))) void*)(uintptr_t)g,
      (__attribute__((address_space(3))) void*)(uint32_t)(uintptr_t)lds,
      16, 0, 0);
}

struct Lin {
  const short* p; int ld;
  __device__ __forceinline__ const short* at(int r, int c) const {
    return p + (long)r * ld + c;
  }
};
// oproj A operand: ctx stored as ctx_t[h][i][r*64+d]; m = r*512+i, k = h*64+d
struct CtxMap {
  const short* p;
  __device__ __forceinline__ const short* at(int m, int k) const {
    return p + ((long)((k >> 6) * 512 + (m & 511))) * 4096 + ((m >> 9) << 6) + (k & 63);
  }
};

// ---------------------------------------------------------------------------
// 4-phase-per-K-tile deep-pipelined GEMM core (used by logits/ctx/oproj).
// BM=256, BN=128, BK=64. 512 threads = 8 waves (4M x 2N). (r3 core, proven.)
// ---------------------------------------------------------------------------
template<class AT, class BT>
__device__ __forceinline__ void gemm_core(
    const AT& A, const BT& B, int m0, int n0, int K,
    short* smem, f32x4 (&acc)[4][4])
{
  const int t = threadIdx.x, l = t & 63, w = t >> 6;
  const int wm = w >> 1, wn = w & 1;
  const int g_row8 = t >> 3;
  const int cg = t & 7;

  auto stageA = [&](int kt, int buf, int u){
    const int row = u*64 + g_row8;
    const int sc  = ((cg ^ (row & 7)) << 3);
    gload16(A.at(m0 + row, kt*64 + sc), smem + buf*16384 + u*4096 + w*512);
  };
  auto stageB = [&](int kt, int buf, int u){
    const int row = u*64 + g_row8;
    const int sc  = ((cg ^ (row & 7)) << 3);
    gload16(B.at(n0 + row, kt*64 + sc), smem + 49152 + buf*8192 + u*4096 + w*512);
  };

  const int NT = K >> 6;
  #pragma unroll
  for (int u = 0; u < 4; ++u) stageA(0, 0, u);
  #pragma unroll
  for (int u = 0; u < 2; ++u) stageB(0, 0, u);
  #pragma unroll
  for (int u = 0; u < 4; ++u) stageA(1, 1, u);
  #pragma unroll
  for (int u = 0; u < 2; ++u) stageB(1, 1, u);
  asm volatile("s_waitcnt vmcnt(6)" ::: "memory");
  __builtin_amdgcn_s_barrier();
  asm volatile("" ::: "memory");

  int cur = 0;
  for (int kt = 0; kt < NT; ++kt){
    const int tgt = (cur == 0) ? 2 : cur - 1;
    const bool pf = (kt + 2 < NT);
    const char* cA = (const char*)(smem + cur * 16384);
    const char* cB = (const char*)(smem + 49152 + cur * 8192);

    auto rdA = [&](int m, int ks)->short8{
      const int r = wm*64 + m*16 + (l & 15);
      const int g = (ks*4 + (l >> 4)) ^ (r & 7);
      return *(const short8*)(cA + r*128 + g*16);
    };
    auto rdB = [&](int n, int ks)->short8{
      const int r = wn*64 + n*16 + (l & 15);
      const int g = (ks*4 + (l >> 4)) ^ (r & 7);
      return *(const short8*)(cB + r*128 + g*16);
    };

    short8 af0a, af0b, af1a, af1b, af2a, af2b, af3a, af3b;
    short8 bf0a, bf0b, bf1a, bf1b, bf2a, bf2b, bf3a, bf3b;

    // phase 0
    af0a = rdA(0,0); af0b = rdA(0,1); af1a = rdA(1,0); af1b = rdA(1,1);
    bf0a = rdB(0,0); bf0b = rdB(0,1); bf1a = rdB(1,0); bf1b = rdB(1,1);
    if (pf){ stageA(kt+2, tgt, 0); stageA(kt+2, tgt, 1); }
    __builtin_amdgcn_s_barrier();
    __builtin_amdgcn_sched_barrier(0);
    __builtin_amdgcn_s_setprio(1);
    acc[0][0] = MFMA16(af0a, bf0a, acc[0][0]); acc[0][0] = MFMA16(af0b, bf0b, acc[0][0]);
    acc[0][1] = MFMA16(af0a, bf1a, acc[0][1]); acc[0][1] = MFMA16(af0b, bf1b, acc[0][1]);
    acc[1][0] = MFMA16(af1a, bf0a, acc[1][0]); acc[1][0] = MFMA16(af1b, bf0b, acc[1][0]);
    acc[1][1] = MFMA16(af1a, bf1a, acc[1][1]); acc[1][1] = MFMA16(af1b, bf1b, acc[1][1]);
    __builtin_amdgcn_s_setprio(0);
    __builtin_amdgcn_s_barrier();
    asm volatile("" ::: "memory");

    // phase 1
    bf2a = rdB(2,0); bf2b = rdB(2,1); bf3a = rdB(3,0); bf3b = rdB(3,1);
    if (pf){ stageA(kt+2, tgt, 2); stageA(kt+2, tgt, 3); }
    __builtin_amdgcn_s_barrier();
    __builtin_amdgcn_sched_barrier(0);
    __builtin_amdgcn_s_setprio(1);
    acc[0][2] = MFMA16(af0a, bf2a, acc[0][2]); acc[0][2] = MFMA16(af0b, bf2b, acc[0][2]);
    acc[0][3] = MFMA16(af0a, bf3a, acc[0][3]); acc[0][3] = MFMA16(af0b, bf3b, acc[0][3]);
    acc[1][2] = MFMA16(af1a, bf2a, acc[1][2]); acc[1][2] = MFMA16(af1b, bf2b, acc[1][2]);
    acc[1][3] = MFMA16(af1a, bf3a, acc[1][3]); acc[1][3] = MFMA16(af1b, bf3b, acc[1][3]);
    __builtin_amdgcn_s_setprio(0);
    __builtin_amdgcn_s_barrier();
    asm volatile("" ::: "memory");

    // phase 2
    af2a = rdA(2,0); af2b = rdA(2,1); af3a = rdA(3,0); af3b = rdA(3,1);
    if (pf){ stageB(kt+2, tgt, 0); stageB(kt+2, tgt, 1); }
    __builtin_amdgcn_s_barrier();
    __builtin_amdgcn_sched_barrier(0);
    __builtin_amdgcn_s_setprio(1);
    acc[2][2] = MFMA16(af2a, bf2a, acc[2][2]); acc[2][2] = MFMA16(af2b, bf2b, acc[2][2]);
    acc[2][3] = MFMA16(af2a, bf3a, acc[2][3]); acc[2][3] = MFMA16(af2b, bf3b, acc[2][3]);
    acc[3][2] = MFMA16(af3a, bf2a, acc[3][2]); acc[3][2] = MFMA16(af3b, bf2b, acc[3][2]);
    acc[3][3] = MFMA16(af3a, bf3a, acc[3][3]); acc[3][3] = MFMA16(af3b, bf3b, acc[3][3]);
    __builtin_amdgcn_s_setprio(0);
    __builtin_amdgcn_s_barrier();
    asm volatile("" ::: "memory");

    // phase 3
    __builtin_amdgcn_s_setprio(1);
    acc[2][0] = MFMA16(af2a, bf0a, acc[2][0]); acc[2][0] = MFMA16(af2b, bf0b, acc[2][0]);
    acc[2][1] = MFMA16(af2a, bf1a, acc[2][1]); acc[2][1] = MFMA16(af2b, bf1b, acc[2][1]);
    acc[3][0] = MFMA16(af3a, bf0a, acc[3][0]); acc[3][0] = MFMA16(af3b, bf0b, acc[3][0]);
    acc[3][1] = MFMA16(af3a, bf1a, acc[3][1]); acc[3][1] = MFMA16(af3b, bf1b, acc[3][1]);
    __builtin_amdgcn_s_setprio(0);
    if (pf) asm volatile("s_waitcnt vmcnt(6)" ::: "memory");
    else    asm volatile("s_waitcnt vmcnt(0)" ::: "memory");
    __builtin_amdgcn_s_barrier();
    asm volatile("" ::: "memory");
    cur = (cur == 2) ? 0 : cur + 1;
  }
}

#define ACC_INIT(acc) \
  _Pragma("unroll") for (int m_=0;m_<4;m_++) _Pragma("unroll") for (int n_=0;n_<4;n_++) \
    acc[m_][n_] = (f32x4){0.f,0.f,0.f,0.f};

// ---------------------------------------------------------------------------
__global__ __launch_bounds__(256) void cvt_k(
    const float* __restrict__ in, short* __restrict__ out, int n8, float scale)
{
  int i = blockIdx.x * blockDim.x + threadIdx.x;
  const int stride = gridDim.x * blockDim.x;
  for (; i < n8; i += stride){
    floatv4 a = *(const floatv4*)(in + (long)i*8);
    floatv4 b = *(const floatv4*)(in + (long)i*8 + 4);
    short8 s;
    #pragma unroll
    for (int j = 0; j < 4; ++j){ s[j] = f2bf(a[j]*scale); s[4+j] = f2bf(b[j]*scale); }
    *(short8*)(out + (long)i*8) = s;
  }
}

__global__ __launch_bounds__(256) void cvt_w_k(
    const float* __restrict__ Wq, const float* __restrict__ Wk,
    const float* __restrict__ Wv, const float* __restrict__ Wo,
    short* __restrict__ out)
{
  const int i = blockIdx.x * blockDim.x + threadIdx.x;
  const int wsel = i / 73728, j = i - wsel * 73728;
  const float* src = (wsel == 0) ? Wq : (wsel == 1) ? Wk : (wsel == 2) ? Wv : Wo;
  const float scale = (wsel == 0) ? 0.015625f : 1.0f;
  floatv4 a = *(const floatv4*)(src + (long)j*8);
  floatv4 b = *(const floatv4*)(src + (long)j*8 + 4);
  short8 s;
  #pragma unroll
  for (int q = 0; q < 4; ++q){ s[q] = f2bf(a[q]*scale); s[4+q] = f2bf(b[q]*scale); }
  *(short8*)(out + (long)i*8) = s;
}

// ---------------------------------------------------------------------------
// Fused q/k/v projection (r6 structure, staging/swizzle identical), compute
// switched to v_mfma_f32_32x32x16_bf16: per phase 8 MFMA (2m x 2n x 2k)
// instead of 16 -- half the issue slots, higher pipe ceiling (2382 vs 2075).
// A-frag layout (K-doubling rule): row = l&31, k = (l>>5)*8 + e.
// C/D layout (HW-verified m74/m101): col = l&31,
//   row = (reg&3) + 8*(reg>>2) + 4*(l>>5), reg in [0,16).
// BM=256, BN=128 (x3 proj), BK=32. LDS as r6 (120 KB, 3-slot, vmcnt(5)).
// ---------------------------------------------------------------------------
__global__ __launch_bounds__(512, 2) void proj_fused_k(
    const short* __restrict__ xb, const short* __restrict__ wb,
    const float* __restrict__ bq, const float* __restrict__ bk, const float* __restrict__ bv,
    short* __restrict__ qt, short* __restrict__ kt, short* __restrict__ vtt)
{
  __shared__ short smem[61440];
  const int bid = blockIdx.x;
  const int xcd = bid & 7, idx = bid >> 3;        // idx 0..95
  const int mlocal = idx / 6, n = idx % 6;
  const int m0 = (xcd * 16 + mlocal) * 256;
  const int n0 = n * 128;

  const int t = threadIdx.x, l = t & 63, w = t >> 6;
  const int wm = w >> 1, wn = w & 1;

  const int lsub = l >> 3;           // line within instr (0..7)
  const int sslot = l & 7;           // slot within line

  Lin A{xb, E_};

  auto stageA = [&](int kt_, int buf, int u){
    const int L = (w*2 + u)*8 + lsub;            // line 0..127
    const int v = sslot ^ (L & 7);
    const int row = L*2 + (v >> 2);
    const int g = v & 3;
    gload16(A.at(m0 + row, kt_*32 + g*8), smem + buf*8192 + (w*2 + u)*512);
  };
  auto stageB = [&](int kt_, int buf, int p){
    const int L = w*8 + lsub;                    // line 0..63
    const int v = sslot ^ (L & 7);
    const int row = L*2 + (v >> 2);
    const int g = v & 3;
    gload16(wb + (long)p*E_*E_ + (long)(n0 + row)*E_ + kt_*32 + g*8,
            smem + 24576 + buf*12288 + p*4096 + w*512);
  };

  f32x16 acc[3][2][2];
  #pragma unroll
  for (int p = 0; p < 3; ++p)
    #pragma unroll
    for (int mm = 0; mm < 2; ++mm)
      #pragma unroll
      for (int nn = 0; nn < 2; ++nn)
        #pragma unroll
        for (int e = 0; e < 16; ++e) acc[p][mm][nn][e] = 0.f;

  const int NT = E_ / 32;   // 24
  stageA(0,0,0); stageA(0,0,1); stageB(0,0,0); stageB(0,0,1); stageB(0,0,2);
  stageA(1,1,0); stageA(1,1,1); stageB(1,1,0); stageB(1,1,1); stageB(1,1,2);
  asm volatile("s_waitcnt vmcnt(5)" ::: "memory");
  __builtin_amdgcn_s_barrier();
  asm volatile("" ::: "memory");

  int cur = 0;
  for (int kt_ = 0; kt_ < NT; ++kt_){
    const int tgt = (cur == 0) ? 2 : cur - 1;
    const bool pf = (kt_ + 2 < NT);
    const char* cA = (const char*)(smem + cur * 8192);
    const char* cB = (const char*)(smem + 24576 + cur * 12288);

    // 32x32x16 A-frag: rows (l&31), k = ks*16 + (l>>5)*8 .. +8
    auto rdA = [&](int mm, int ks)->short8{
      const int r = wm*64 + mm*32 + (l & 31);
      const int g = ks*2 + (l >> 5);             // 16B group within 32-k row
      const int L = r >> 1;
      const int s = ((r & 1)*4 + g) ^ (L & 7);
      return *(const short8*)(cA + L*128 + s*16);
    };
    auto rdB = [&](int p, int nn, int ks)->short8{
      const int r = wn*64 + nn*32 + (l & 31);
      const int g = ks*2 + (l >> 5);
      const int L = r >> 1;
      const int s = ((r & 1)*4 + g) ^ (L & 7);
      return *(const short8*)(cB + p*8192 + L*128 + s*16);
    };

    short8 a00, a01, a10, a11;    // a[mm][ks]
    short8 b00, b01, b10, b11;    // b[nn][ks]

    // ---- phase 0: proj q. read A + Bq frags; stage A u0,u1 (t+2)
    a00 = rdA(0,0); a01 = rdA(0,1); a10 = rdA(1,0); a11 = rdA(1,1);
    b00 = rdB(0,0,0); b01 = rdB(0,0,1); b10 = rdB(0,1,0); b11 = rdB(0,1,1);
    if (pf){ stageA(kt_+2, tgt, 0); stageA(kt_+2, tgt, 1); }
    __builtin_amdgcn_s_barrier();
    __builtin_amdgcn_sched_barrier(0);
    __builtin_amdgcn_s_setprio(1);
    acc[0][0][0] = MFMA32(a00, b00, acc[0][0][0]); acc[0][0][0] = MFMA32(a01, b01, acc[0][0][0]);
    acc[0][0][1] = MFMA32(a00, b10, acc[0][0][1]); acc[0][0][1] = MFMA32(a01, b11, acc[0][0][1]);
    acc[0][1][0] = MFMA32(a10, b00, acc[0][1][0]); acc[0][1][0] = MFMA32(a11, b01, acc[0][1][0]);
    acc[0][1][1] = MFMA32(a10, b10, acc[0][1][1]); acc[0][1][1] = MFMA32(a11, b11, acc[0][1][1]);
    __builtin_amdgcn_s_setprio(0);
    __builtin_amdgcn_s_barrier();
    asm volatile("" ::: "memory");

    // ---- phase 1: proj k. read Bk frags; stage B p0,p1 (t+2)
    b00 = rdB(1,0,0); b01 = rdB(1,0,1); b10 = rdB(1,1,0); b11 = rdB(1,1,1);
    if (pf){ stageB(kt_+2, tgt, 0); stageB(kt_+2, tgt, 1); }
    __builtin_amdgcn_s_barrier();
    __builtin_amdgcn_sched_barrier(0);
    __builtin_amdgcn_s_setprio(1);
    acc[1][0][0] = MFMA32(a00, b00, acc[1][0][0]); acc[1][0][0] = MFMA32(a01, b01, acc[1][0][0]);
    acc[1][0][1] = MFMA32(a00, b10, acc[1][0][1]); acc[1][0][1] = MFMA32(a01, b11, acc[1][0][1]);
    acc[1][1][0] = MFMA32(a10, b00, acc[1][1][0]); acc[1][1][0] = MFMA32(a11, b01, acc[1][1][0]);
    acc[1][1][1] = MFMA32(a10, b10, acc[1][1][1]); acc[1][1][1] = MFMA32(a11, b11, acc[1][1][1]);
    __builtin_amdgcn_s_setprio(0);
    __builtin_amdgcn_s_barrier();
    asm volatile("" ::: "memory");

    // ---- phase 2: proj v. read Bv frags; stage B p2 (t+2); boundary wait
    b00 = rdB(2,0,0); b01 = rdB(2,0,1); b10 = rdB(2,1,0); b11 = rdB(2,1,1);
    if (pf){ stageB(kt_+2, tgt, 2); }
    __builtin_amdgcn_s_barrier();
    __builtin_amdgcn_sched_barrier(0);
    __builtin_amdgcn_s_setprio(1);
    acc[2][0][0] = MFMA32(a00, b00, acc[2][0][0]); acc[2][0][0] = MFMA32(a01, b01, acc[2][0][0]);
    acc[2][0][1] = MFMA32(a00, b10, acc[2][0][1]); acc[2][0][1] = MFMA32(a01, b11, acc[2][0][1]);
    acc[2][1][0] = MFMA32(a10, b00, acc[2][1][0]); acc[2][1][0] = MFMA32(a11, b01, acc[2][1][0]);
    acc[2][1][1] = MFMA32(a10, b10, acc[2][1][1]); acc[2][1][1] = MFMA32(a11, b11, acc[2][1][1]);
    __builtin_amdgcn_s_setprio(0);
    if (pf) asm volatile("s_waitcnt vmcnt(5)" ::: "memory");
    else    asm volatile("s_waitcnt vmcnt(0)" ::: "memory");
    __builtin_amdgcn_s_barrier();
    asm volatile("" ::: "memory");
    cur = (cur == 2) ? 0 : cur + 1;
  }

  // ---------------- epilogue (32x32 C/D layout) ----------------
  const int wr = wm * 64, wc = wn * 64;
  const int r = m0 >> 9, i0 = m0 & 511;
  const int lrow4 = 4*(l >> 5);                  // 0 or 4

  // q, k: direct scatter (64B d-runs per 32 lanes)
  #pragma unroll
  for (int p = 0; p < 2; ++p){
    const float* bias = (p == 0) ? bq : bk;
    short* outp = (p == 0) ? qt : kt;
    const float sc = (p == 0) ? 0.015625f : 1.0f;
    #pragma unroll
    for (int nn = 0; nn < 2; ++nn){
      const int gc = n0 + wc + nn*32 + (l & 31);
      const float bb = bias[gc] * sc;
      const int h = gc >> 6, d = gc & 63;
      #pragma unroll
      for (int mm = 0; mm < 2; ++mm){
        #pragma unroll
        for (int rq = 0; rq < 4; ++rq){
          #pragma unroll
          for (int rg = 0; rg < 4; ++rg){
            const int gm = m0 + wr + mm*32 + rq*8 + lrow4 + rg;
            const int i = gm & 511;
            outp[((long)(h*512 + i))*4096 + r*64 + d] =
                f2bf(acc[p][mm][nn][rq*4 + rg] + bb);
          }
        }
      }
    }
  }

  // v: LDS bounce -> coalesced vtt[h][r*64+d][j] rows.
  {
    short* ldsv = smem;
    #pragma unroll
    for (int nn = 0; nn < 2; ++nn){
      const int dl = wc + nn*32 + (l & 31);
      const float bb = bv[n0 + dl];
      #pragma unroll
      for (int mm = 0; mm < 2; ++mm){
        #pragma unroll
        for (int rq = 0; rq < 4; ++rq){
          const int j0 = wr + mm*32 + rq*8 + lrow4;
          short4v s;
          #pragma unroll
          for (int rg = 0; rg < 4; ++rg) s[rg] = f2bf(acc[2][mm][nn][rq*4 + rg] + bb);
          const int byteoff = dl*512 + (((j0 >> 3) ^ (dl & 31)) << 4) + (j0 & 7)*2;
          *(short4v*)((char*)ldsv + byteoff) = s;
        }
      }
    }
    __builtin_amdgcn_s_barrier();
    const int dl = t & 127, chunk = t >> 7;     // 4 chunks of 64 shorts
    const int gd = n0 + dl;
    const int h = gd >> 6, dd = gd & 63;
    short* dst = vtt + ((long)h*4096 + r*64 + dd)*512 + i0 + chunk*64;
    #pragma unroll
    for (int q = 0; q < 8; ++q){
      const int c16 = chunk*8 + q;
      short8 vv = *(const short8*)((const char*)ldsv + dl*512 + ((c16 ^ (dl & 31)) << 4));
      *(short8*)(dst + q*8) = vv;
    }
  }
}

// ---------------------------------------------------------------------------
// Logits split-K x2. 1-D grid 192; z-grouped on XCDs. Partials -> out scratch.
// ---------------------------------------------------------------------------
__global__ __launch_bounds__(512, 2) void logits_k(
    const short* __restrict__ qt, const short* __restrict__ kt,
    float* __restrict__ P0, float* __restrict__ P1)
{
  __shared__ short smem[73728];
  const int bid = blockIdx.x;
  const int xcd = bid & 7, idx = bid >> 3;        // idx 0..23
  const int z = xcd * 3 + idx / 8;                // 0..23
  const int local = idx & 7;
  const int h = z >> 1, s = z & 1;
  const int m0 = (local >> 2) * 256, n0 = (local & 3) * 128;

  f32x4 acc[4][4]; ACC_INIT(acc);
  Lin A{qt + (long)h * C_ * 4096 + s*2048, 4096};
  Lin B{kt + (long)h * C_ * 4096 + s*2048, 4096};
  gemm_core(A, B, m0, n0, 2048, smem, acc);

  float* Sh = ((s == 0) ? P0 : P1) + (long)h * C_ * C_;
  const int t = threadIdx.x, l = t & 63, w = t >> 6;
  const int wr = (w >> 1) * 64, wc = (w & 1) * 64;
  #pragma unroll
  for (int m = 0; m < 4; ++m){
    #pragma unroll
    for (int n = 0; n < 4; ++n){
      #pragma unroll
      for (int rg = 0; rg < 4; ++rg){
        const int gi = m0 + wr + m*16 + (l >> 4)*4 + rg;
        const int gj = n0 + wc + n*16 + (l & 15);
        Sh[(long)gi * C_ + gj] = acc[m][n][rg];
      }
    }
  }
}

// ---------------------------------------------------------------------------
__global__ __launch_bounds__(256) void softmax4_k(
    const float* __restrict__ S0, const float* __restrict__ S1,
    float* __restrict__ probs, short* __restrict__ Pbf)
{
  const int row = blockIdx.x;       // h*512 + i
  const int i = row & 511;
  const long base = (long)row * C_;
  const int t = threadIdx.x, lane = t & 63, wid = t >> 6;
  __shared__ float red[4];

  float v0 = S0[base + t]       + S1[base + t];
  float v1 = S0[base + t + 256] + S1[base + t + 256];
  if (t == i)       v0 = -1e9f;
  if (t + 256 == i) v1 = -1e9f;

  float mx = fmaxf(v0, v1);
  #pragma unroll
  for (int m = 1; m < 64; m <<= 1) mx = fmaxf(mx, __shfl_xor(mx, m, 64));
  if (lane == 0) red[wid] = mx;
  __syncthreads();
  mx = fmaxf(fmaxf(red[0], red[1]), fmaxf(red[2], red[3]));
  __syncthreads();

  float e0 = __expf(v0 - mx), e1 = __expf(v1 - mx);
  float ssum = e0 + e1;
  #pragma unroll
  for (int m = 1; m < 64; m <<= 1) ssum += __shfl_xor(ssum, m, 64);
  if (lane == 0) red[wid] = ssum;
  __syncthreads();
  const float inv = 1.0f / (red[0] + red[1] + red[2] + red[3]);

  const float p0 = e0 * inv, p1 = e1 * inv;
  probs[base + t] = p0; probs[base + t + 256] = p1;
  Pbf[base + t] = f2bf(p0);
  Pbf[base + t + 256] = f2bf(p1);
}

// ---------------------------------------------------------------------------
__global__ __launch_bounds__(512, 2) void ctx_k(
    const short* __restrict__ pb, const short* __restrict__ vtt, short* __restrict__ ctx_t)
{
  __shared__ short smem[73728];
  const int bid = blockIdx.x;
  const int seq = (bid & 7) * 96 + (bid >> 3);    // 0..767
  const int h = seq >> 6, local = seq & 63;
  const int m0 = (local >> 5) * 256, n0 = (local & 31) * 128;

  f32x4 acc[4][4]; ACC_INIT(acc);
  Lin A{pb + (long)h * C_ * C_, C_};
  Lin B{vtt + (long)h * 4096 * C_, C_};
  gemm_core(A, B, m0, n0, C_, smem, acc);

  const int t = threadIdx.x, l = t & 63, w = t >> 6;
  const int wr = (w >> 1) * 64, wc = (w & 1) * 64;
  short* outh = ctx_t + (long)h * C_ * 4096;
  #pragma unroll
  for (int m = 0; m < 4; ++m){
    #pragma unroll
    for (int n = 0; n < 4; ++n){
      #pragma unroll
      for (int rg = 0; rg < 4; ++rg){
        const int gi = m0 + wr + m*16 + (l >> 4)*4 + rg;
        const int gn = n0 + wc + n*16 + (l & 15);
        outh[(long)gi * 4096 + gn] = f2bf(acc[m][n][rg]);
      }
    }
  }
}

// ---------------------------------------------------------------------------
__global__ __launch_bounds__(512, 2) void oproj_k(
    const short* __restrict__ ctx_t, const short* __restrict__ wo,
    const float* __restrict__ bo, float* __restrict__ out)
{
  __shared__ short smem[73728];
  const int bid = blockIdx.x;
  const int xcd = bid & 7, idx = bid >> 3;        // 0..95
  const int m0 = (xcd * 16 + idx / 6) * 256;
  const int n0 = (idx % 6) * 128;

  f32x4 acc[4][4]; ACC_INIT(acc);
  CtxMap A{ctx_t};
  Lin B{wo, E_};
  gemm_core(A, B, m0, n0, E_, smem, acc);

  const int t = threadIdx.x, l = t & 63, w = t >> 6;
  const int wr = (w >> 1) * 64, wc = (w & 1) * 64;
  #pragma unroll
  for (int n = 0; n < 4; ++n){
    const int gc = n0 + wc + n*16 + (l & 15);
    const float bb = bo[gc];
    #pragma unroll
    for (int m = 0; m < 4; ++m){
      #pragma unroll
      for (int rg = 0; rg < 4; ++rg){
        const int gm = m0 + wr + m*16 + (l >> 4)*4 + rg;
        out[(long)gm * E_ + gc] = acc[m][n][rg] + bb;
      }
    }
  }
}

// ---------------------------------------------------------------------------
extern "C" void kernel_launch(void* const* d_in, const int* in_sizes, int n_in,
                              void* d_out, int out_size, void* d_ws, size_t ws_size,
                              hipStream_t stream)
{
  const float* x  = (const float*)d_in[0];
  const float* Wq = (const float*)d_in[2];
  const float* bq = (const float*)d_in[3];
  const float* Wk = (const float*)d_in[4];
  const float* bk = (const float*)d_in[5];
  const float* Wv = (const float*)d_in[6];
  const float* bv = (const float*)d_in[7];
  const float* Wo = (const float*)d_in[8];
  const float* bo = (const float*)d_in[9];
  const float* l  = (const float*)d_in[10];

  float* out   = (float*)d_out;                          // [32768][768]
  float* probs = out + (size_t)M_TOT * E_;               // [12][512][512] f32
  float* lout  = probs + (size_t)H_ * C_ * C_;           // [12]

  // out-region scratch (dead until oproj): two logits partials + vtt
  float* P0  = out;                                      // 12.6 MB
  float* P1  = out + 3145728;                            // 12.6 MB
  short* vtt = (short*)(out + 6291456);                  // 50.3 MB bf16

  short* ws_s = (short*)d_ws;
  const size_t SLOT = (size_t)M_TOT * E_;                // 25,165,824 elems
  short* s0 = ws_s;                // xb
  short* s1 = ws_s + SLOT;         // qt -> ctx_t
  short* s2 = ws_s + 2*SLOT;       // kt -> pb
  short* wb = ws_s + 3*SLOT;       // 4 x 589824 bf16 weights

  hipMemcpyAsync(lout, l, H_ * sizeof(float), hipMemcpyDeviceToDevice, stream);

  cvt_k<<<2048, 256, 0, stream>>>(x, s0, (int)(SLOT/8), 1.0f);
  cvt_w_k<<<1152, 256, 0, stream>>>(Wq, Wk, Wv, Wo, wb);

  proj_fused_k<<<768, 512, 0, stream>>>(s0, wb, bq, bk, bv, s1, s2, vtt);
  logits_k<<<192, 512, 0, stream>>>(s1, s2, P0, P1);
  softmax4_k<<<H_ * C_, 256, 0, stream>>>(P0, P1, probs, s2);
  ctx_k<<<768, 512, 0, stream>>>(s2, vtt, s1);
  oproj_k<<<768, 512, 0, stream>>>(s1, wb + 3*589824, bo, out);
}

// Round 13
// 294.206 us; speedup vs baseline: 1.2216x; 1.0412x over previous
//
#include <hip/hip_runtime.h>
#include <stdint.h>

#define R_ 64
#define C_ 512
#define E_ 768
#define H_ 12
#define D_ 64
#define M_TOT (R_*C_)   // 32768

using short4v = __attribute__((ext_vector_type(4))) short;
using short8  = __attribute__((ext_vector_type(8))) short;
using f32x4   = __attribute__((ext_vector_type(4))) float;
using floatv4 = __attribute__((ext_vector_type(4))) float;

#define MFMA16(a,b,c) __builtin_amdgcn_mfma_f32_16x16x32_bf16(a,b,c,0,0,0)

__device__ __forceinline__ short f2bf(float f){
  union { float f; unsigned u; } c; c.f = f;
  unsigned u = c.u;
  u += 0x7fffu + ((u >> 16) & 1u);   // RNE
  return (short)(u >> 16);
}
__device__ __forceinline__ float b2f(short s){
  union { unsigned u; float f; } c;
  c.u = ((unsigned)(unsigned short)s) << 16;
  return c.f;
}

// async global->LDS, 16B per lane. LDS dest is wave-uniform base; HW adds lane*16.
__device__ __forceinline__ void gload16(const void* g, void* lds){
  __builtin_amdgcn_global_load_lds(
      (const __attribute__((address_space(1))) void*)(uintptr_t)g,
      (__attribute__((address_space(3))) void*)(uint32_t)(uintptr_t)lds,
      16, 0, 0);
}

struct Lin {
  const short* p; int ld;
  __device__ __forceinline__ const short* at(int r, int c) const {
    return p + (long)r * ld + c;
  }
};
// oproj A operand: ctx stored as ctx_t[h][i][r*64+d]; m = r*512+i, k = h*64+d
struct CtxMap {
  const short* p;
  __device__ __forceinline__ const short* at(int m, int k) const {
    return p + ((long)((k >> 6) * 512 + (m & 511))) * 4096 + ((m >> 9) << 6) + (k & 63);
  }
};

// ---------------------------------------------------------------------------
// 4-phase-per-K-tile deep-pipelined GEMM core (used by logits/ctx/oproj).
// BM=256, BN=128, BK=64. 512 threads = 8 waves (4M x 2N). (r3 core, proven.)
// ---------------------------------------------------------------------------
template<class AT, class BT>
__device__ __forceinline__ void gemm_core(
    const AT& A, const BT& B, int m0, int n0, int K,
    short* smem, f32x4 (&acc)[4][4])
{
  const int t = threadIdx.x, l = t & 63, w = t >> 6;
  const int wm = w >> 1, wn = w & 1;
  const int g_row8 = t >> 3;
  const int cg = t & 7;

  auto stageA = [&](int kt, int buf, int u){
    const int row = u*64 + g_row8;
    const int sc  = ((cg ^ (row & 7)) << 3);
    gload16(A.at(m0 + row, kt*64 + sc), smem + buf*16384 + u*4096 + w*512);
  };
  auto stageB = [&](int kt, int buf, int u){
    const int row = u*64 + g_row8;
    const int sc  = ((cg ^ (row & 7)) << 3);
    gload16(B.at(n0 + row, kt*64 + sc), smem + 49152 + buf*8192 + u*4096 + w*512);
  };

  const int NT = K >> 6;
  #pragma unroll
  for (int u = 0; u < 4; ++u) stageA(0, 0, u);
  #pragma unroll
  for (int u = 0; u < 2; ++u) stageB(0, 0, u);
  #pragma unroll
  for (int u = 0; u < 4; ++u) stageA(1, 1, u);
  #pragma unroll
  for (int u = 0; u < 2; ++u) stageB(1, 1, u);
  asm volatile("s_waitcnt vmcnt(6)" ::: "memory");
  __builtin_amdgcn_s_barrier();
  asm volatile("" ::: "memory");

  int cur = 0;
  for (int kt = 0; kt < NT; ++kt){
    const int tgt = (cur == 0) ? 2 : cur - 1;
    const bool pf = (kt + 2 < NT);
    const char* cA = (const char*)(smem + cur * 16384);
    const char* cB = (const char*)(smem + 49152 + cur * 8192);

    auto rdA = [&](int m, int ks)->short8{
      const int r = wm*64 + m*16 + (l & 15);
      const int g = (ks*4 + (l >> 4)) ^ (r & 7);
      return *(const short8*)(cA + r*128 + g*16);
    };
    auto rdB = [&](int n, int ks)->short8{
      const int r = wn*64 + n*16 + (l & 15);
      const int g = (ks*4 + (l >> 4)) ^ (r & 7);
      return *(const short8*)(cB + r*128 + g*16);
    };

    short8 af0a, af0b, af1a, af1b, af2a, af2b, af3a, af3b;
    short8 bf0a, bf0b, bf1a, bf1b, bf2a, bf2b, bf3a, bf3b;

    // phase 0
    af0a = rdA(0,0); af0b = rdA(0,1); af1a = rdA(1,0); af1b = rdA(1,1);
    bf0a = rdB(0,0); bf0b = rdB(0,1); bf1a = rdB(1,0); bf1b = rdB(1,1);
    if (pf){ stageA(kt+2, tgt, 0); stageA(kt+2, tgt, 1); }
    __builtin_amdgcn_s_barrier();
    __builtin_amdgcn_sched_barrier(0);
    __builtin_amdgcn_s_setprio(1);
    acc[0][0] = MFMA16(af0a, bf0a, acc[0][0]); acc[0][0] = MFMA16(af0b, bf0b, acc[0][0]);
    acc[0][1] = MFMA16(af0a, bf1a, acc[0][1]); acc[0][1] = MFMA16(af0b, bf1b, acc[0][1]);
    acc[1][0] = MFMA16(af1a, bf0a, acc[1][0]); acc[1][0] = MFMA16(af1b, bf0b, acc[1][0]);
    acc[1][1] = MFMA16(af1a, bf1a, acc[1][1]); acc[1][1] = MFMA16(af1b, bf1b, acc[1][1]);
    __builtin_amdgcn_s_setprio(0);
    __builtin_amdgcn_s_barrier();
    asm volatile("" ::: "memory");

    // phase 1
    bf2a = rdB(2,0); bf2b = rdB(2,1); bf3a = rdB(3,0); bf3b = rdB(3,1);
    if (pf){ stageA(kt+2, tgt, 2); stageA(kt+2, tgt, 3); }
    __builtin_amdgcn_s_barrier();
    __builtin_amdgcn_sched_barrier(0);
    __builtin_amdgcn_s_setprio(1);
    acc[0][2] = MFMA16(af0a, bf2a, acc[0][2]); acc[0][2] = MFMA16(af0b, bf2b, acc[0][2]);
    acc[0][3] = MFMA16(af0a, bf3a, acc[0][3]); acc[0][3] = MFMA16(af0b, bf3b, acc[0][3]);
    acc[1][2] = MFMA16(af1a, bf2a, acc[1][2]); acc[1][2] = MFMA16(af1b, bf2b, acc[1][2]);
    acc[1][3] = MFMA16(af1a, bf3a, acc[1][3]); acc[1][3] = MFMA16(af1b, bf3b, acc[1][3]);
    __builtin_amdgcn_s_setprio(0);
    __builtin_amdgcn_s_barrier();
    asm volatile("" ::: "memory");

    // phase 2
    af2a = rdA(2,0); af2b = rdA(2,1); af3a = rdA(3,0); af3b = rdA(3,1);
    if (pf){ stageB(kt+2, tgt, 0); stageB(kt+2, tgt, 1); }
    __builtin_amdgcn_s_barrier();
    __builtin_amdgcn_sched_barrier(0);
    __builtin_amdgcn_s_setprio(1);
    acc[2][2] = MFMA16(af2a, bf2a, acc[2][2]); acc[2][2] = MFMA16(af2b, bf2b, acc[2][2]);
    acc[2][3] = MFMA16(af2a, bf3a, acc[2][3]); acc[2][3] = MFMA16(af2b, bf3b, acc[2][3]);
    acc[3][2] = MFMA16(af3a, bf2a, acc[3][2]); acc[3][2] = MFMA16(af3b, bf2b, acc[3][2]);
    acc[3][3] = MFMA16(af3a, bf3a, acc[3][3]); acc[3][3] = MFMA16(af3b, bf3b, acc[3][3]);
    __builtin_amdgcn_s_setprio(0);
    __builtin_amdgcn_s_barrier();
    asm volatile("" ::: "memory");

    // phase 3
    __builtin_amdgcn_s_setprio(1);
    acc[2][0] = MFMA16(af2a, bf0a, acc[2][0]); acc[2][0] = MFMA16(af2b, bf0b, acc[2][0]);
    acc[2][1] = MFMA16(af2a, bf1a, acc[2][1]); acc[2][1] = MFMA16(af2b, bf1b, acc[2][1]);
    acc[3][0] = MFMA16(af3a, bf0a, acc[3][0]); acc[3][0] = MFMA16(af3b, bf0b, acc[3][0]);
    acc[3][1] = MFMA16(af3a, bf1a, acc[3][1]); acc[3][1] = MFMA16(af3b, bf1b, acc[3][1]);
    __builtin_amdgcn_s_setprio(0);
    if (pf) asm volatile("s_waitcnt vmcnt(6)" ::: "memory");
    else    asm volatile("s_waitcnt vmcnt(0)" ::: "memory");
    __builtin_amdgcn_s_barrier();
    asm volatile("" ::: "memory");
    cur = (cur == 2) ? 0 : cur + 1;
  }
}

#define ACC_INIT(acc) \
  _Pragma("unroll") for (int m_=0;m_<4;m_++) _Pragma("unroll") for (int n_=0;n_<4;n_++) \
    acc[m_][n_] = (f32x4){0.f,0.f,0.f,0.f};

// ---------------------------------------------------------------------------
__global__ __launch_bounds__(256) void cvt_k(
    const float* __restrict__ in, short* __restrict__ out, int n8, float scale)
{
  int i = blockIdx.x * blockDim.x + threadIdx.x;
  const int stride = gridDim.x * blockDim.x;
  for (; i < n8; i += stride){
    floatv4 a = *(const floatv4*)(in + (long)i*8);
    floatv4 b = *(const floatv4*)(in + (long)i*8 + 4);
    short8 s;
    #pragma unroll
    for (int j = 0; j < 4; ++j){ s[j] = f2bf(a[j]*scale); s[4+j] = f2bf(b[j]*scale); }
    *(short8*)(out + (long)i*8) = s;
  }
}

__global__ __launch_bounds__(256) void cvt_w_k(
    const float* __restrict__ Wq, const float* __restrict__ Wk,
    const float* __restrict__ Wv, const float* __restrict__ Wo,
    short* __restrict__ out)
{
  const int i = blockIdx.x * blockDim.x + threadIdx.x;
  const int wsel = i / 73728, j = i - wsel * 73728;
  const float* src = (wsel == 0) ? Wq : (wsel == 1) ? Wk : (wsel == 2) ? Wv : Wo;
  const float scale = (wsel == 0) ? 0.015625f : 1.0f;
  floatv4 a = *(const floatv4*)(src + (long)j*8);
  floatv4 b = *(const floatv4*)(src + (long)j*8 + 4);
  short8 s;
  #pragma unroll
  for (int q = 0; q < 4; ++q){ s[q] = f2bf(a[q]*scale); s[4+q] = f2bf(b[q]*scale); }
  *(short8*)(out + (long)i*8) = s;
}

// ---------------------------------------------------------------------------
// Fused q/k/v projection (r6 best structure, byte-identical).
// BM=256, BN=128 (x3 proj), BK=32. LDS 120 KB, 3-slot, vmcnt(5).
// ---------------------------------------------------------------------------
__global__ __launch_bounds__(512, 2) void proj_fused_k(
    const short* __restrict__ xb, const short* __restrict__ wb,
    const float* __restrict__ bq, const float* __restrict__ bk, const float* __restrict__ bv,
    short* __restrict__ qt, short* __restrict__ kt, short* __restrict__ vtt)
{
  __shared__ short smem[61440];
  const int bid = blockIdx.x;
  const int xcd = bid & 7, idx = bid >> 3;        // idx 0..95
  const int mlocal = idx / 6, n = idx % 6;
  const int m0 = (xcd * 16 + mlocal) * 256;
  const int n0 = n * 128;

  const int t = threadIdx.x, l = t & 63, w = t >> 6;
  const int wm = w >> 1, wn = w & 1;

  const int lsub = l >> 3;           // line within instr (0..7)
  const int sslot = l & 7;           // slot within line

  Lin A{xb, E_};

  auto stageA = [&](int kt_, int buf, int u){
    const int L = (w*2 + u)*8 + lsub;            // line 0..127
    const int v = sslot ^ (L & 7);
    const int row = L*2 + (v >> 2);
    const int g = v & 3;
    gload16(A.at(m0 + row, kt_*32 + g*8), smem + buf*8192 + (w*2 + u)*512);
  };
  auto stageB = [&](int kt_, int buf, int p){
    const int L = w*8 + lsub;                    // line 0..63
    const int v = sslot ^ (L & 7);
    const int row = L*2 + (v >> 2);
    const int g = v & 3;
    gload16(wb + (long)p*E_*E_ + (long)(n0 + row)*E_ + kt_*32 + g*8,
            smem + 24576 + buf*12288 + p*4096 + w*512);
  };

  f32x4 acc[3][4][4];
  #pragma unroll
  for (int p = 0; p < 3; ++p) ACC_INIT(acc[p]);

  const int NT = E_ / 32;   // 24
  stageA(0,0,0); stageA(0,0,1); stageB(0,0,0); stageB(0,0,1); stageB(0,0,2);
  stageA(1,1,0); stageA(1,1,1); stageB(1,1,0); stageB(1,1,1); stageB(1,1,2);
  asm volatile("s_waitcnt vmcnt(5)" ::: "memory");
  __builtin_amdgcn_s_barrier();
  asm volatile("" ::: "memory");

  int cur = 0;
  for (int kt_ = 0; kt_ < NT; ++kt_){
    const int tgt = (cur == 0) ? 2 : cur - 1;
    const bool pf = (kt_ + 2 < NT);
    const char* cA = (const char*)(smem + cur * 8192);
    const char* cB = (const char*)(smem + 24576 + cur * 12288);

    auto rdA = [&](int m)->short8{
      const int r = wm*64 + m*16 + (l & 15);
      const int g = l >> 4;
      const int L = r >> 1;
      const int s = ((r & 1)*4 + g) ^ (L & 7);
      return *(const short8*)(cA + L*128 + s*16);
    };
    auto rdB = [&](int p, int nn)->short8{
      const int r = wn*64 + nn*16 + (l & 15);
      const int g = l >> 4;
      const int L = r >> 1;
      const int s = ((r & 1)*4 + g) ^ (L & 7);
      return *(const short8*)(cB + p*8192 + L*128 + s*16);
    };

    short8 af0, af1, af2, af3, b0, b1, b2, b3;

    // ---- phase 0: proj q
    af0 = rdA(0); af1 = rdA(1); af2 = rdA(2); af3 = rdA(3);
    b0 = rdB(0,0); b1 = rdB(0,1); b2 = rdB(0,2); b3 = rdB(0,3);
    if (pf){ stageA(kt_+2, tgt, 0); stageA(kt_+2, tgt, 1); }
    __builtin_amdgcn_s_barrier();
    __builtin_amdgcn_sched_barrier(0);
    __builtin_amdgcn_s_setprio(1);
    acc[0][0][0] = MFMA16(af0, b0, acc[0][0][0]); acc[0][0][1] = MFMA16(af0, b1, acc[0][0][1]);
    acc[0][0][2] = MFMA16(af0, b2, acc[0][0][2]); acc[0][0][3] = MFMA16(af0, b3, acc[0][0][3]);
    acc[0][1][0] = MFMA16(af1, b0, acc[0][1][0]); acc[0][1][1] = MFMA16(af1, b1, acc[0][1][1]);
    acc[0][1][2] = MFMA16(af1, b2, acc[0][1][2]); acc[0][1][3] = MFMA16(af1, b3, acc[0][1][3]);
    acc[0][2][0] = MFMA16(af2, b0, acc[0][2][0]); acc[0][2][1] = MFMA16(af2, b1, acc[0][2][1]);
    acc[0][2][2] = MFMA16(af2, b2, acc[0][2][2]); acc[0][2][3] = MFMA16(af2, b3, acc[0][2][3]);
    acc[0][3][0] = MFMA16(af3, b0, acc[0][3][0]); acc[0][3][1] = MFMA16(af3, b1, acc[0][3][1]);
    acc[0][3][2] = MFMA16(af3, b2, acc[0][3][2]); acc[0][3][3] = MFMA16(af3, b3, acc[0][3][3]);
    __builtin_amdgcn_s_setprio(0);
    __builtin_amdgcn_s_barrier();
    asm volatile("" ::: "memory");

    // ---- phase 1: proj k
    b0 = rdB(1,0); b1 = rdB(1,1); b2 = rdB(1,2); b3 = rdB(1,3);
    if (pf){ stageB(kt_+2, tgt, 0); stageB(kt_+2, tgt, 1); }
    __builtin_amdgcn_s_barrier();
    __builtin_amdgcn_sched_barrier(0);
    __builtin_amdgcn_s_setprio(1);
    acc[1][0][0] = MFMA16(af0, b0, acc[1][0][0]); acc[1][0][1] = MFMA16(af0, b1, acc[1][0][1]);
    acc[1][0][2] = MFMA16(af0, b2, acc[1][0][2]); acc[1][0][3] = MFMA16(af0, b3, acc[1][0][3]);
    acc[1][1][0] = MFMA16(af1, b0, acc[1][1][0]); acc[1][1][1] = MFMA16(af1, b1, acc[1][1][1]);
    acc[1][1][2] = MFMA16(af1, b2, acc[1][1][2]); acc[1][1][3] = MFMA16(af1, b3, acc[1][1][3]);
    acc[1][2][0] = MFMA16(af2, b0, acc[1][2][0]); acc[1][2][1] = MFMA16(af2, b1, acc[1][2][1]);
    acc[1][2][2] = MFMA16(af2, b2, acc[1][2][2]); acc[1][2][3] = MFMA16(af2, b3, acc[1][2][3]);
    acc[1][3][0] = MFMA16(af3, b0, acc[1][3][0]); acc[1][3][1] = MFMA16(af3, b1, acc[1][3][1]);
    acc[1][3][2] = MFMA16(af3, b2, acc[1][3][2]); acc[1][3][3] = MFMA16(af3, b3, acc[1][3][3]);
    __builtin_amdgcn_s_setprio(0);
    __builtin_amdgcn_s_barrier();
    asm volatile("" ::: "memory");

    // ---- phase 2: proj v
    b0 = rdB(2,0); b1 = rdB(2,1); b2 = rdB(2,2); b3 = rdB(2,3);
    if (pf){ stageB(kt_+2, tgt, 2); }
    __builtin_amdgcn_s_barrier();
    __builtin_amdgcn_sched_barrier(0);
    __builtin_amdgcn_s_setprio(1);
    acc[2][0][0] = MFMA16(af0, b0, acc[2][0][0]); acc[2][0][1] = MFMA16(af0, b1, acc[2][0][1]);
    acc[2][0][2] = MFMA16(af0, b2, acc[2][0][2]); acc[2][0][3] = MFMA16(af0, b3, acc[2][0][3]);
    acc[2][1][0] = MFMA16(af1, b0, acc[2][1][0]); acc[2][1][1] = MFMA16(af1, b1, acc[2][1][1]);
    acc[2][1][2] = MFMA16(af1, b2, acc[2][1][2]); acc[2][1][3] = MFMA16(af1, b3, acc[2][1][3]);
    acc[2][2][0] = MFMA16(af2, b0, acc[2][2][0]); acc[2][2][1] = MFMA16(af2, b1, acc[2][2][1]);
    acc[2][2][2] = MFMA16(af2, b2, acc[2][2][2]); acc[2][2][3] = MFMA16(af2, b3, acc[2][2][3]);
    acc[2][3][0] = MFMA16(af3, b0, acc[2][3][0]); acc[2][3][1] = MFMA16(af3, b1, acc[2][3][1]);
    acc[2][3][2] = MFMA16(af3, b2, acc[2][3][2]); acc[2][3][3] = MFMA16(af3, b3, acc[2][3][3]);
    __builtin_amdgcn_s_setprio(0);
    if (pf) asm volatile("s_waitcnt vmcnt(5)" ::: "memory");
    else    asm volatile("s_waitcnt vmcnt(0)" ::: "memory");
    __builtin_amdgcn_s_barrier();
    asm volatile("" ::: "memory");
    cur = (cur == 2) ? 0 : cur + 1;
  }

  // ---------------- epilogue ----------------
  const int wr = wm * 64, wc = wn * 64;

  // q, k: direct scatter
  #pragma unroll
  for (int p = 0; p < 2; ++p){
    const float* bias = (p == 0) ? bq : bk;
    short* outp = (p == 0) ? qt : kt;
    const float sc = (p == 0) ? 0.015625f : 1.0f;
    #pragma unroll
    for (int nn = 0; nn < 4; ++nn){
      const int gc = n0 + wc + nn*16 + (l & 15);
      const float bb = bias[gc] * sc;
      const int h = gc >> 6, d = gc & 63;
      #pragma unroll
      for (int m = 0; m < 4; ++m){
        #pragma unroll
        for (int rg = 0; rg < 4; ++rg){
          const int gm = m0 + wr + m*16 + (l >> 4)*4 + rg;
          const int i = gm & 511, r = gm >> 9;
          outp[((long)(h*512 + i))*4096 + r*64 + d] = f2bf(acc[p][m][nn][rg] + bb);
        }
      }
    }
  }

  // v: LDS bounce -> coalesced vtt[h][r*64+d][j] rows.
  {
    short* ldsv = smem;
    #pragma unroll
    for (int nn = 0; nn < 4; ++nn){
      const int dl = wc + nn*16 + (l & 15);
      const float bb = bv[n0 + dl];
      #pragma unroll
      for (int m = 0; m < 4; ++m){
        const int j = wr + m*16 + (l >> 4)*4;
        short4v s;
        #pragma unroll
        for (int rg = 0; rg < 4; ++rg) s[rg] = f2bf(acc[2][m][nn][rg] + bb);
        const int byteoff = dl*512 + (((j >> 3) ^ (dl & 31)) << 4) + (j & 7)*2;
        *(short4v*)((char*)ldsv + byteoff) = s;
      }
    }
    __builtin_amdgcn_s_barrier();
    const int dl = t & 127, chunk = t >> 7;     // 4 chunks of 64 shorts
    const int gd = n0 + dl;
    const int h = gd >> 6, dd = gd & 63;
    const int r = m0 >> 9, i0 = m0 & 511;
    short* dst = vtt + ((long)h*4096 + r*64 + dd)*512 + i0 + chunk*64;
    #pragma unroll
    for (int q = 0; q < 8; ++q){
      const int c16 = chunk*8 + q;
      short8 vv = *(const short8*)((const char*)ldsv + dl*512 + ((c16 ^ (dl & 31)) << 4));
      *(short8*)(dst + q*8) = vv;
    }
  }
}

// ---------------------------------------------------------------------------
// Logits split-K x2. 1-D grid 192; z-grouped on XCDs. Partials -> out scratch
// as BF16 (halves intermediate HBM traffic; logits ~N(0,0.31), bf16 error
// ~1e-3 absolute -> probs error ~1e-4, 300x under threshold).
// ---------------------------------------------------------------------------
__global__ __launch_bounds__(512, 2) void logits_k(
    const short* __restrict__ qt, const short* __restrict__ kt,
    short* __restrict__ P0, short* __restrict__ P1)
{
  __shared__ short smem[73728];
  const int bid = blockIdx.x;
  const int xcd = bid & 7, idx = bid >> 3;        // idx 0..23
  const int z = xcd * 3 + idx / 8;                // 0..23
  const int local = idx & 7;
  const int h = z >> 1, s = z & 1;
  const int m0 = (local >> 2) * 256, n0 = (local & 3) * 128;

  f32x4 acc[4][4]; ACC_INIT(acc);
  Lin A{qt + (long)h * C_ * 4096 + s*2048, 4096};
  Lin B{kt + (long)h * C_ * 4096 + s*2048, 4096};
  gemm_core(A, B, m0, n0, 2048, smem, acc);

  short* Sh = ((s == 0) ? P0 : P1) + (long)h * C_ * C_;
  const int t = threadIdx.x, l = t & 63, w = t >> 6;
  const int wr = (w >> 1) * 64, wc = (w & 1) * 64;
  #pragma unroll
  for (int m = 0; m < 4; ++m){
    #pragma unroll
    for (int n = 0; n < 4; ++n){
      #pragma unroll
      for (int rg = 0; rg < 4; ++rg){
        const int gi = m0 + wr + m*16 + (l >> 4)*4 + rg;
        const int gj = n0 + wc + n*16 + (l & 15);
        Sh[(long)gi * C_ + gj] = f2bf(acc[m][n][rg]);
      }
    }
  }
}

// ---------------------------------------------------------------------------
// softmax: sum 2 bf16 partials, mask diag, softmax -> probs f32 + bf16 copy.
// ---------------------------------------------------------------------------
__global__ __launch_bounds__(256) void softmax4_k(
    const short* __restrict__ S0, const short* __restrict__ S1,
    float* __restrict__ probs, short* __restrict__ Pbf)
{
  const int row = blockIdx.x;       // h*512 + i
  const int i = row & 511;
  const long base = (long)row * C_;
  const int t = threadIdx.x, lane = t & 63, wid = t >> 6;
  __shared__ float red[4];

  float v0 = b2f(S0[base + t])       + b2f(S1[base + t]);
  float v1 = b2f(S0[base + t + 256]) + b2f(S1[base + t + 256]);
  if (t == i)       v0 = -1e9f;
  if (t + 256 == i) v1 = -1e9f;

  float mx = fmaxf(v0, v1);
  #pragma unroll
  for (int m = 1; m < 64; m <<= 1) mx = fmaxf(mx, __shfl_xor(mx, m, 64));
  if (lane == 0) red[wid] = mx;
  __syncthreads();
  mx = fmaxf(fmaxf(red[0], red[1]), fmaxf(red[2], red[3]));
  __syncthreads();

  float e0 = __expf(v0 - mx), e1 = __expf(v1 - mx);
  float ssum = e0 + e1;
  #pragma unroll
  for (int m = 1; m < 64; m <<= 1) ssum += __shfl_xor(ssum, m, 64);
  if (lane == 0) red[wid] = ssum;
  __syncthreads();
  const float inv = 1.0f / (red[0] + red[1] + red[2] + red[3]);

  const float p0 = e0 * inv, p1 = e1 * inv;
  probs[base + t] = p0; probs[base + t + 256] = p1;
  Pbf[base + t] = f2bf(p0);
  Pbf[base + t + 256] = f2bf(p1);
}

// ---------------------------------------------------------------------------
__global__ __launch_bounds__(512, 2) void ctx_k(
    const short* __restrict__ pb, const short* __restrict__ vtt, short* __restrict__ ctx_t)
{
  __shared__ short smem[73728];
  const int bid = blockIdx.x;
  const int seq = (bid & 7) * 96 + (bid >> 3);    // 0..767
  const int h = seq >> 6, local = seq & 63;
  const int m0 = (local >> 5) * 256, n0 = (local & 31) * 128;

  f32x4 acc[4][4]; ACC_INIT(acc);
  Lin A{pb + (long)h * C_ * C_, C_};
  Lin B{vtt + (long)h * 4096 * C_, C_};
  gemm_core(A, B, m0, n0, C_, smem, acc);

  const int t = threadIdx.x, l = t & 63, w = t >> 6;
  const int wr = (w >> 1) * 64, wc = (w & 1) * 64;
  short* outh = ctx_t + (long)h * C_ * 4096;
  #pragma unroll
  for (int m = 0; m < 4; ++m){
    #pragma unroll
    for (int n = 0; n < 4; ++n){
      #pragma unroll
      for (int rg = 0; rg < 4; ++rg){
        const int gi = m0 + wr + m*16 + (l >> 4)*4 + rg;
        const int gn = n0 + wc + n*16 + (l & 15);
        outh[(long)gi * 4096 + gn] = f2bf(acc[m][n][rg]);
      }
    }
  }
}

// ---------------------------------------------------------------------------
__global__ __launch_bounds__(512, 2) void oproj_k(
    const short* __restrict__ ctx_t, const short* __restrict__ wo,
    const float* __restrict__ bo, float* __restrict__ out)
{
  __shared__ short smem[73728];
  const int bid = blockIdx.x;
  const int xcd = bid & 7, idx = bid >> 3;        // 0..95
  const int m0 = (xcd * 16 + idx / 6) * 256;
  const int n0 = (idx % 6) * 128;

  f32x4 acc[4][4]; ACC_INIT(acc);
  CtxMap A{ctx_t};
  Lin B{wo, E_};
  gemm_core(A, B, m0, n0, E_, smem, acc);

  const int t = threadIdx.x, l = t & 63, w = t >> 6;
  const int wr = (w >> 1) * 64, wc = (w & 1) * 64;
  #pragma unroll
  for (int n = 0; n < 4; ++n){
    const int gc = n0 + wc + n*16 + (l & 15);
    const float bb = bo[gc];
    #pragma unroll
    for (int m = 0; m < 4; ++m){
      #pragma unroll
      for (int rg = 0; rg < 4; ++rg){
        const int gm = m0 + wr + m*16 + (l >> 4)*4 + rg;
        out[(long)gm * E_ + gc] = acc[m][n][rg] + bb;
      }
    }
  }
}

// ---------------------------------------------------------------------------
extern "C" void kernel_launch(void* const* d_in, const int* in_sizes, int n_in,
                              void* d_out, int out_size, void* d_ws, size_t ws_size,
                              hipStream_t stream)
{
  const float* x  = (const float*)d_in[0];
  const float* Wq = (const float*)d_in[2];
  const float* bq = (const float*)d_in[3];
  const float* Wk = (const float*)d_in[4];
  const float* bk = (const float*)d_in[5];
  const float* Wv = (const float*)d_in[6];
  const float* bv = (const float*)d_in[7];
  const float* Wo = (const float*)d_in[8];
  const float* bo = (const float*)d_in[9];
  const float* l  = (const float*)d_in[10];

  float* out   = (float*)d_out;                          // [32768][768]
  float* probs = out + (size_t)M_TOT * E_;               // [12][512][512] f32
  float* lout  = probs + (size_t)H_ * C_ * C_;           // [12]

  // out-region scratch (dead until oproj): two bf16 logits partials + vtt
  short* P0  = (short*)out;                              // 6.3 MB bf16
  short* P1  = (short*)out + 3145728;                    // 6.3 MB bf16
  short* vtt = (short*)(out + 6291456);                  // 50.3 MB bf16

  short* ws_s = (short*)d_ws;
  const size_t SLOT = (size_t)M_TOT * E_;                // 25,165,824 elems
  short* s0 = ws_s;                // xb
  short* s1 = ws_s + SLOT;         // qt -> ctx_t
  short* s2 = ws_s + 2*SLOT;       // kt -> pb
  short* wb = ws_s + 3*SLOT;       // 4 x 589824 bf16 weights

  hipMemcpyAsync(lout, l, H_ * sizeof(float), hipMemcpyDeviceToDevice, stream);

  cvt_k<<<2048, 256, 0, stream>>>(x, s0, (int)(SLOT/8), 1.0f);
  cvt_w_k<<<1152, 256, 0, stream>>>(Wq, Wk, Wv, Wo, wb);

  proj_fused_k<<<768, 512, 0, stream>>>(s0, wb, bq, bk, bv, s1, s2, vtt);
  logits_k<<<192, 512, 0, stream>>>(s1, s2, P0, P1);
  softmax4_k<<<H_ * C_, 256, 0, stream>>>(P0, P1, probs, s2);
  ctx_k<<<768, 512, 0, stream>>>(s2, vtt, s1);
  oproj_k<<<768, 512, 0, stream>>>(s1, wb + 3*589824, bo, out);
}